// Round 10
// baseline (80.073 us; speedup 1.0000x reference)
//
#include <hip/hip_runtime.h>

// SimpleHybridModel via MFMA, all-transposed chaining (no lane shuffles):
//  conv1d(k=3,SAME,relu) -> SimpleRNN(16,tanh) -> dense(8,relu) -> dense(1)
//
// R10 changes vs R9 (phase split; R9 still ~80% VALU/chain-bound):
//  - Phase A (unroll 4): per l, ds_read_b128 -> conv MFMA -> relu+pkrtz ->
//    B2s[l] (f16x4). Independent across l -> full software pipelining.
//  - Phase B (full unroll): a2 = MFMA(A2,B2s[l],rbp) [H-independent, issues
//    ahead] -> a2 = MFMA(AU,H,a2) -> tanh -> H. Serial chain shrunk from
//    (ds_read+3 MFMA+tanh) to (1 MFMA+tanh) per step.
//  - B2s = 40 VGPRs, static indices only; __launch_bounds__(256,4) lifts the
//    VGPR cap to 128 (the ,6 cap of ~85 would spill).
// R8/R9 design retained: 16B rows (one ds_read_b128/iter), bias rides MFMA
// k=31 vs dummy-1.0 half, 2*log2e folded into A2/AU/rnn_b, packed cvts,
// row-per-thread staging, head via 4th MFMA.

#define BLK 256   // 4 waves; each wave owns 16 batch elements
#define LSEQ 20
#define EPD 92    // dwords per element: 23 rows (r=-1..21) * 4 dwords (8 halves)
#define LOG2E2 2.8853900817779268f   // 2*log2(e)

typedef _Float16 f16;
typedef __fp16   fp16x2 __attribute__((ext_vector_type(2)));   // cvt_pkrtz result type
typedef _Float16 f16x4 __attribute__((ext_vector_type(4)));
typedef _Float16 f16x8 __attribute__((ext_vector_type(8)));
typedef float    f32x4 __attribute__((ext_vector_type(4)));

union UB128 { uint4 q; f16x8 v; };
union UB64  { f16x4 v; fp16x2 p[2]; };
union HU    { fp16x2 p; uint u; };

__global__ __launch_bounds__(BLK, 4) void hybrid_fwd(
    const float* __restrict__ x,
    const float* __restrict__ conv_w, const float* __restrict__ conv_b,
    const float* __restrict__ rnn_w,  const float* __restrict__ rnn_u,
    const float* __restrict__ rnn_b,
    const float* __restrict__ d1_w,   const float* __restrict__ d1_b,
    const float* __restrict__ out_w,  const float* __restrict__ out_b,
    float* __restrict__ out)
{
    __shared__ __align__(16) uint xs[64 * EPD];   // 23552 B

    const int tid  = threadIdx.x;
    const int wave = tid >> 6, lane = tid & 63;
    const int b16  = lane & 15, g = lane >> 4;
    const long BE  = (long)blockIdx.x * 64;

    // ---- init rows -1 (dw 0..3), 20,21 (dw 84..91); dummy half (f=7) = 1.0 ----
    #pragma unroll
    for (int k = 0; k < 3; ++k) {
        int t = tid + k * BLK;                    // 768 = 64 elems * 12 dwords
        int e = t / 12, s = t - e * 12;
        xs[e * EPD + (s < 4 ? s : 80 + s)] = ((s & 3) == 3) ? 0x3C000000u : 0u;
    }
    // ---- stage x: row-per-thread; 1280 tasks = 5 rounds ----
    const float* xg = x + BE * 140;
    #pragma unroll 2
    for (int k = 0; k < 5; ++k) {
        int t = tid + k * BLK;
        int e = t / 20, r = t - e * 20;
        const float* rp = xg + e * 140 + r * 7;
        float f0 = rp[0], f1 = rp[1], f2 = rp[2], f3 = rp[3];
        float f4 = rp[4], f5 = rp[5], f6 = rp[6];
        HU h0, h1, h2, h3;
        h0.p = __builtin_amdgcn_cvt_pkrtz(f0, f1);
        h1.p = __builtin_amdgcn_cvt_pkrtz(f2, f3);
        h2.p = __builtin_amdgcn_cvt_pkrtz(f4, f5);
        h3.p = __builtin_amdgcn_cvt_pkrtz(f6, 1.0f);   // f7 dummy = 1.0 (bias lane)
        uint4 val; val.x = h0.u; val.y = h1.u; val.z = h2.u; val.w = h3.u;
        *(uint4*)&xs[e * EPD + 4 * (r + 1)] = val;     // 16B aligned
    }
    __syncthreads();

    // ---- weight fragments (register-resident, loaded once) ----
    // A1[m=co=b16, k=8g+t]: g = conv tap (0..2), t = feature (0..6);
    // k==31 -> conv_b (pairs with B1's 1.0 dummy); other slots 0.
    f16x8 A1;
    #pragma unroll
    for (int t = 0; t < 8; ++t) {
        float wv = conv_w[min(g * 7 + t, 20) * 16 + b16];
        float sel = (g < 3 && t < 7) ? wv
                  : ((g == 3 && t == 7) ? conv_b[b16] : 0.f);
        A1[t] = (f16)sel;
    }
    // A2/AU/rb scaled by 2*log2(e): a2 = 2log2e*s, so e^{2s} = exp2(a2).
    f16x4 A2, AU;
    f32x4 rbp;
    #pragma unroll
    for (int t = 0; t < 4; ++t) {
        A2[t]  = (f16)(LOG2E2 * rnn_w[(4 * g + t) * 16 + b16]);
        AU[t]  = (f16)(LOG2E2 * rnn_u[(4 * g + t) * 16 + b16]);
        rbp[t] = LOG2E2 * rnn_b[4 * g + t];
    }
    const f32x4 zero4 = {0.f, 0.f, 0.f, 0.f};

    // per-lane read base: element (wave*16+b16), tap-group offset 4g dwords
    const uint* rbase = xs + (wave * 16 + b16) * EPD + 4 * g;

    // ---- Phase A: conv + relu for all l (independent -> full pipelining) ----
    f16x4 B2s[LSEQ];                 // 40 VGPRs, static indices only
    #pragma unroll 4
    for (int l = 0; l < LSEQ; ++l) {
        UB128 B1;
        B1.q = *(const uint4*)(rbase + 4 * l);   // rows l-1+g, one b128
        f32x4 a1 = __builtin_amdgcn_mfma_f32_16x16x32_f16(A1, B1.v, zero4, 0, 0, 0);
        UB64 B2;
        B2.p[0] = __builtin_amdgcn_cvt_pkrtz(fmaxf(a1[0], 0.f), fmaxf(a1[1], 0.f));
        B2.p[1] = __builtin_amdgcn_cvt_pkrtz(fmaxf(a1[2], 0.f), fmaxf(a1[3], 0.f));
        B2s[l] = B2.v;
    }

    // ---- Phase B: serial recurrence (chain = 1 MFMA + tanh per step) ----
    f16x4 H = {};
    #pragma unroll
    for (int l = 0; l < LSEQ; ++l) {
        f32x4 a2 = __builtin_amdgcn_mfma_f32_16x16x16f16(A2, B2s[l], rbp, 0, 0, 0);
        a2 = __builtin_amdgcn_mfma_f32_16x16x16f16(AU, H, a2, 0, 0, 0);
        // tanh(s) = 1 - 2*rcp(1 + exp2(a2));  a2 = 2log2e*s
        float t0 = __builtin_amdgcn_rcpf(1.f + __builtin_amdgcn_exp2f(a2[0]));
        float t1 = __builtin_amdgcn_rcpf(1.f + __builtin_amdgcn_exp2f(a2[1]));
        float t2 = __builtin_amdgcn_rcpf(1.f + __builtin_amdgcn_exp2f(a2[2]));
        float t3 = __builtin_amdgcn_rcpf(1.f + __builtin_amdgcn_exp2f(a2[3]));
        UB64 Hn;
        Hn.p[0] = __builtin_amdgcn_cvt_pkrtz(fmaf(-2.f, t0, 1.f), fmaf(-2.f, t1, 1.f));
        Hn.p[1] = __builtin_amdgcn_cvt_pkrtz(fmaf(-2.f, t2, 1.f), fmaf(-2.f, t3, 1.f));
        H = Hn.v;
    }

    // ---- head via MFMA: z^T[d][b] = sum_j d1_w[j][d]*H[j][b] + d1_b[d] ----
    f16x4 A3;
    f32x4 c3;
    #pragma unroll
    for (int t = 0; t < 4; ++t) {
        int j = 4 * g + t;
        A3[t] = (f16)(b16 < 8 ? d1_w[j * 8 + b16] : 0.f);
        c3[t] = d1_b[min(j, 7)];                 // rows>=8 garbage (finite)
    }
    f32x4 a3 = __builtin_amdgcn_mfma_f32_16x16x16f16(A3, H, c3, 0, 0, 0);
    float part = 0.f;
    #pragma unroll
    for (int r = 0; r < 4; ++r) {
        int d = 4 * g + r;                       // valid for g<2
        float wv = (g < 2) ? out_w[min(d, 7)] : 0.f;
        part = fmaf(fmaxf(a3[r], 0.f), wv, part);
    }
    part += __shfl_xor(part, 16);                // sum over g
    part += __shfl_xor(part, 32);
    if (lane < 16)
        out[BE + wave * 16 + lane] = part + out_b[0];
}

extern "C" void kernel_launch(void* const* d_in, const int* in_sizes, int n_in,
                              void* d_out, int out_size, void* d_ws, size_t ws_size,
                              hipStream_t stream) {
    const float* x      = (const float*)d_in[0];
    const float* conv_w = (const float*)d_in[1];
    const float* conv_b = (const float*)d_in[2];
    const float* rnn_w  = (const float*)d_in[3];
    const float* rnn_u  = (const float*)d_in[4];
    const float* rnn_b  = (const float*)d_in[5];
    const float* d1_w   = (const float*)d_in[6];
    const float* d1_b   = (const float*)d_in[7];
    const float* out_w  = (const float*)d_in[8];
    const float* out_b  = (const float*)d_in[9];
    float* out = (float*)d_out;

    const int B = out_size;                 // 262144
    const int grid = B / 64;                // 4096 blocks (4 waves * 16 elems)
    hybrid_fwd<<<grid, BLK, 0, stream>>>(x, conv_w, conv_b, rnn_w, rnn_u, rnn_b,
                                         d1_w, d1_b, out_w, out_b, out);
}

// Round 11
// 46.346 us; speedup vs baseline: 1.7277x; 1.7277x over previous
//
#include <hip/hip_runtime.h>

// SimpleHybridModel via MFMA, all-transposed chaining (no lane shuffles):
//  conv1d(k=3,SAME,relu) -> SimpleRNN(16,tanh) -> dense(8,relu) -> dense(1)
//
// R11 = R10 with Phase A FULLY unrolled. R10's "#pragma unroll 4" left B2s[l]
// runtime-indexed -> the array went to SCRATCH (VGPR=40, WRITE_SIZE 165MB =
// 1M threads x 160B, dur 80us). Full unroll makes every B2s index static ->
// register-resident (rule: runtime-indexed ext_vector arrays go to scratch).
//
// Phase split rationale (unchanged): conv MFMA + relu are independent across
// l -> pipeline freely; only MFMA(AU,H)+tanh is serial. Serial chain per step
// shrinks from (ds_read + 3 MFMA + tanh) to (1 MFMA + tanh).
// R8/R9 design retained: 16B rows (one ds_read_b128/iter), bias rides MFMA
// k=31 vs dummy-1.0 half, 2*log2e folded into A2/AU/rnn_b, packed cvts,
// row-per-thread staging, head via 4th MFMA.

#define BLK 256   // 4 waves; each wave owns 16 batch elements
#define LSEQ 20
#define EPD 92    // dwords per element: 23 rows (r=-1..21) * 4 dwords (8 halves)
#define LOG2E2 2.8853900817779268f   // 2*log2(e)

typedef _Float16 f16;
typedef __fp16   fp16x2 __attribute__((ext_vector_type(2)));   // cvt_pkrtz result type
typedef _Float16 f16x4 __attribute__((ext_vector_type(4)));
typedef _Float16 f16x8 __attribute__((ext_vector_type(8)));
typedef float    f32x4 __attribute__((ext_vector_type(4)));

union UB128 { uint4 q; f16x8 v; };
union UB64  { f16x4 v; fp16x2 p[2]; };
union HU    { fp16x2 p; uint u; };

__global__ __launch_bounds__(BLK, 4) void hybrid_fwd(
    const float* __restrict__ x,
    const float* __restrict__ conv_w, const float* __restrict__ conv_b,
    const float* __restrict__ rnn_w,  const float* __restrict__ rnn_u,
    const float* __restrict__ rnn_b,
    const float* __restrict__ d1_w,   const float* __restrict__ d1_b,
    const float* __restrict__ out_w,  const float* __restrict__ out_b,
    float* __restrict__ out)
{
    __shared__ __align__(16) uint xs[64 * EPD];   // 23552 B

    const int tid  = threadIdx.x;
    const int wave = tid >> 6, lane = tid & 63;
    const int b16  = lane & 15, g = lane >> 4;
    const long BE  = (long)blockIdx.x * 64;

    // ---- init rows -1 (dw 0..3), 20,21 (dw 84..91); dummy half (f=7) = 1.0 ----
    #pragma unroll
    for (int k = 0; k < 3; ++k) {
        int t = tid + k * BLK;                    // 768 = 64 elems * 12 dwords
        int e = t / 12, s = t - e * 12;
        xs[e * EPD + (s < 4 ? s : 80 + s)] = ((s & 3) == 3) ? 0x3C000000u : 0u;
    }
    // ---- stage x: row-per-thread; 1280 tasks = 5 rounds ----
    const float* xg = x + BE * 140;
    #pragma unroll 2
    for (int k = 0; k < 5; ++k) {
        int t = tid + k * BLK;
        int e = t / 20, r = t - e * 20;
        const float* rp = xg + e * 140 + r * 7;
        float f0 = rp[0], f1 = rp[1], f2 = rp[2], f3 = rp[3];
        float f4 = rp[4], f5 = rp[5], f6 = rp[6];
        HU h0, h1, h2, h3;
        h0.p = __builtin_amdgcn_cvt_pkrtz(f0, f1);
        h1.p = __builtin_amdgcn_cvt_pkrtz(f2, f3);
        h2.p = __builtin_amdgcn_cvt_pkrtz(f4, f5);
        h3.p = __builtin_amdgcn_cvt_pkrtz(f6, 1.0f);   // f7 dummy = 1.0 (bias lane)
        uint4 val; val.x = h0.u; val.y = h1.u; val.z = h2.u; val.w = h3.u;
        *(uint4*)&xs[e * EPD + 4 * (r + 1)] = val;     // 16B aligned
    }
    __syncthreads();

    // ---- weight fragments (register-resident, loaded once) ----
    // A1[m=co=b16, k=8g+t]: g = conv tap (0..2), t = feature (0..6);
    // k==31 -> conv_b (pairs with B1's 1.0 dummy); other slots 0.
    f16x8 A1;
    #pragma unroll
    for (int t = 0; t < 8; ++t) {
        float wv = conv_w[min(g * 7 + t, 20) * 16 + b16];
        float sel = (g < 3 && t < 7) ? wv
                  : ((g == 3 && t == 7) ? conv_b[b16] : 0.f);
        A1[t] = (f16)sel;
    }
    // A2/AU/rb scaled by 2*log2(e): a2 = 2log2e*s, so e^{2s} = exp2(a2).
    f16x4 A2, AU;
    f32x4 rbp;
    #pragma unroll
    for (int t = 0; t < 4; ++t) {
        A2[t]  = (f16)(LOG2E2 * rnn_w[(4 * g + t) * 16 + b16]);
        AU[t]  = (f16)(LOG2E2 * rnn_u[(4 * g + t) * 16 + b16]);
        rbp[t] = LOG2E2 * rnn_b[4 * g + t];
    }
    const f32x4 zero4 = {0.f, 0.f, 0.f, 0.f};

    // per-lane read base: element (wave*16+b16), tap-group offset 4g dwords
    const uint* rbase = xs + (wave * 16 + b16) * EPD + 4 * g;

    // ---- Phase A: conv + relu for all l, FULL unroll (B2s static-indexed) ----
    f16x4 B2s[LSEQ];                 // 40 VGPRs, all indices compile-time
    #pragma unroll
    for (int l = 0; l < LSEQ; ++l) {
        UB128 B1;
        B1.q = *(const uint4*)(rbase + 4 * l);   // rows l-1+g, one b128
        f32x4 a1 = __builtin_amdgcn_mfma_f32_16x16x32_f16(A1, B1.v, zero4, 0, 0, 0);
        UB64 B2;
        B2.p[0] = __builtin_amdgcn_cvt_pkrtz(fmaxf(a1[0], 0.f), fmaxf(a1[1], 0.f));
        B2.p[1] = __builtin_amdgcn_cvt_pkrtz(fmaxf(a1[2], 0.f), fmaxf(a1[3], 0.f));
        B2s[l] = B2.v;
    }

    // ---- Phase B: serial recurrence (chain = 1 MFMA + tanh per step) ----
    f16x4 H = {};
    #pragma unroll
    for (int l = 0; l < LSEQ; ++l) {
        f32x4 a2 = __builtin_amdgcn_mfma_f32_16x16x16f16(A2, B2s[l], rbp, 0, 0, 0);
        a2 = __builtin_amdgcn_mfma_f32_16x16x16f16(AU, H, a2, 0, 0, 0);
        // tanh(s) = 1 - 2*rcp(1 + exp2(a2));  a2 = 2log2e*s
        float t0 = __builtin_amdgcn_rcpf(1.f + __builtin_amdgcn_exp2f(a2[0]));
        float t1 = __builtin_amdgcn_rcpf(1.f + __builtin_amdgcn_exp2f(a2[1]));
        float t2 = __builtin_amdgcn_rcpf(1.f + __builtin_amdgcn_exp2f(a2[2]));
        float t3 = __builtin_amdgcn_rcpf(1.f + __builtin_amdgcn_exp2f(a2[3]));
        UB64 Hn;
        Hn.p[0] = __builtin_amdgcn_cvt_pkrtz(fmaf(-2.f, t0, 1.f), fmaf(-2.f, t1, 1.f));
        Hn.p[1] = __builtin_amdgcn_cvt_pkrtz(fmaf(-2.f, t2, 1.f), fmaf(-2.f, t3, 1.f));
        H = Hn.v;
    }

    // ---- head via MFMA: z^T[d][b] = sum_j d1_w[j][d]*H[j][b] + d1_b[d] ----
    f16x4 A3;
    f32x4 c3;
    #pragma unroll
    for (int t = 0; t < 4; ++t) {
        int j = 4 * g + t;
        A3[t] = (f16)(b16 < 8 ? d1_w[j * 8 + b16] : 0.f);
        c3[t] = d1_b[min(j, 7)];                 // rows>=8 garbage (finite)
    }
    f32x4 a3 = __builtin_amdgcn_mfma_f32_16x16x16f16(A3, H, c3, 0, 0, 0);
    float part = 0.f;
    #pragma unroll
    for (int r = 0; r < 4; ++r) {
        int d = 4 * g + r;                       // valid for g<2
        float wv = (g < 2) ? out_w[min(d, 7)] : 0.f;
        part = fmaf(fmaxf(a3[r], 0.f), wv, part);
    }
    part += __shfl_xor(part, 16);                // sum over g
    part += __shfl_xor(part, 32);
    if (lane < 16)
        out[BE + wave * 16 + lane] = part + out_b[0];
}

extern "C" void kernel_launch(void* const* d_in, const int* in_sizes, int n_in,
                              void* d_out, int out_size, void* d_ws, size_t ws_size,
                              hipStream_t stream) {
    const float* x      = (const float*)d_in[0];
    const float* conv_w = (const float*)d_in[1];
    const float* conv_b = (const float*)d_in[2];
    const float* rnn_w  = (const float*)d_in[3];
    const float* rnn_u  = (const float*)d_in[4];
    const float* rnn_b  = (const float*)d_in[5];
    const float* d1_w   = (const float*)d_in[6];
    const float* d1_b   = (const float*)d_in[7];
    const float* out_w  = (const float*)d_in[8];
    const float* out_b  = (const float*)d_in[9];
    float* out = (float*)d_out;

    const int B = out_size;                 // 262144
    const int grid = B / 64;                // 4096 blocks (4 waves * 16 elems)
    hybrid_fwd<<<grid, BLK, 0, stream>>>(x, conv_w, conv_b, rnn_w, rnn_u, rnn_b,
                                         d1_w, d1_b, out_w, out_b, out);
}

// Round 12
// 43.597 us; speedup vs baseline: 1.8367x; 1.0631x over previous
//
#include <hip/hip_runtime.h>

// SimpleHybridModel via MFMA, all-transposed chaining (no lane shuffles):
//  conv1d(k=3,SAME,relu) -> SimpleRNN(16,tanh) -> dense(8,relu) -> dense(1)
//
// R12 changes vs R11 (fixed-cost amortization + in-wave ILP):
//  - 2 elements per lane: each wave owns 32 batch elements = two independent
//    16-wide MFMA chains. The recurrence chains interleave -> the serial
//    MFMA(AU,H)+tanh latency of chain 1 hides in chain 0's stalls. Weight
//    setup + staging fixed costs amortized 2x. (R11 counters: VALUBusy 31%,
//    Mfma 7%, occ 60% -> all pipes idle -> per-wave fixed latency dominated.)
//  - all staging/init addressing from shifts only (no integer divides);
//    x loaded as float2 (35 dwordx2 per thread, 8B-aligned).
//  - LDS 47104B -> 3 blocks/CU; __launch_bounds__(256,3) caps VGPR at 170.
// R8-R11 design retained: 16B x-rows (one ds_read_b128 per iter per chain),
// conv bias rides MFMA k=31 against dummy-1.0 half, 2*log2e folded into
// A2/AU/rnn_b, packed cvts, head via MFMA.

#define BLK 256   // 4 waves; each wave owns 32 batch elements (2 per lane)
#define LSEQ 20
#define EPB 128   // elements per block
#define EPD 92    // dwords per element: 23 rows (r=-1..21) * 4 dwords (8 halves)
#define LOG2E2 2.8853900817779268f   // 2*log2(e)

typedef _Float16 f16;
typedef __fp16   fp16x2 __attribute__((ext_vector_type(2)));   // cvt_pkrtz result type
typedef _Float16 f16x4 __attribute__((ext_vector_type(4)));
typedef _Float16 f16x8 __attribute__((ext_vector_type(8)));
typedef float    f32x4 __attribute__((ext_vector_type(4)));

union UB128 { uint4 q; f16x8 v; };
union UB64  { f16x4 v; fp16x2 p[2]; };
union HU    { fp16x2 p; uint u; };

__global__ __launch_bounds__(BLK, 3) void hybrid_fwd(
    const float* __restrict__ x,
    const float* __restrict__ conv_w, const float* __restrict__ conv_b,
    const float* __restrict__ rnn_w,  const float* __restrict__ rnn_u,
    const float* __restrict__ rnn_b,
    const float* __restrict__ d1_w,   const float* __restrict__ d1_b,
    const float* __restrict__ out_w,  const float* __restrict__ out_b,
    float* __restrict__ out)
{
    __shared__ __align__(16) uint xs[EPB * EPD];   // 47104 B

    const int tid  = threadIdx.x;
    const int wave = tid >> 6, lane = tid & 63;
    const int b16  = lane & 15, g = lane >> 4;
    const long BE  = (long)blockIdx.x * EPB;

    const int e = tid >> 1;          // element 0..127 (this thread stages)
    const int q = tid & 1;           // half: rows 10q..10q+9

    // ---- init pad rows -1 (dw 0..3), 20,21 (dw 84..91); dummy f=7 half = 1.0 ----
    {
        uint* eb = xs + e * EPD;
        const uint C = 0x3C000000u;              // (1.0h << 16)
        if (q == 0) {
            uint4 z; z.x = 0u; z.y = 0u; z.z = 0u; z.w = C;
            *(uint4*)(eb + 0) = z;               // row -1
            *(uint2*)(eb + 84) = make_uint2(0u, 0u);
        } else {
            *(uint2*)(eb + 86) = make_uint2(0u, C);   // end row 20
            uint4 z; z.x = 0u; z.y = 0u; z.z = 0u; z.w = C;
            *(uint4*)(eb + 88) = z;              // row 21
        }
    }
    // ---- stage x: 70 consecutive dwords per thread as 35 float2 ----
    {
        const float2* sp = (const float2*)(x + BE * 140 + e * 140 + q * 70);
        float2 f2[35];
        #pragma unroll
        for (int i = 0; i < 35; ++i) f2[i] = sp[i];
        const float* f = (const float*)f2;       // static-indexed below
        uint* eb = xs + e * EPD;
        #pragma unroll
        for (int i = 0; i < 10; ++i) {           // rows r = 10q + i
            HU h0, h1, h2, h3;
            h0.p = __builtin_amdgcn_cvt_pkrtz(f[7 * i + 0], f[7 * i + 1]);
            h1.p = __builtin_amdgcn_cvt_pkrtz(f[7 * i + 2], f[7 * i + 3]);
            h2.p = __builtin_amdgcn_cvt_pkrtz(f[7 * i + 4], f[7 * i + 5]);
            h3.p = __builtin_amdgcn_cvt_pkrtz(f[7 * i + 6], 1.0f);
            uint4 val; val.x = h0.u; val.y = h1.u; val.z = h2.u; val.w = h3.u;
            *(uint4*)(eb + 4 * (10 * q + i + 1)) = val;   // 16B aligned
        }
    }
    __syncthreads();

    // ---- weight fragments (register-resident, loaded once per wave) ----
    f16x8 A1;
    #pragma unroll
    for (int t = 0; t < 8; ++t) {
        float wv = conv_w[min(g * 7 + t, 20) * 16 + b16];
        float sel = (g < 3 && t < 7) ? wv
                  : ((g == 3 && t == 7) ? conv_b[b16] : 0.f);
        A1[t] = (f16)sel;
    }
    f16x4 A2, AU;
    f32x4 rbp;
    #pragma unroll
    for (int t = 0; t < 4; ++t) {
        A2[t]  = (f16)(LOG2E2 * rnn_w[(4 * g + t) * 16 + b16]);
        AU[t]  = (f16)(LOG2E2 * rnn_u[(4 * g + t) * 16 + b16]);
        rbp[t] = LOG2E2 * rnn_b[4 * g + t];
    }
    const f32x4 zero4 = {0.f, 0.f, 0.f, 0.f};

    // per-lane read bases for the two chains
    const uint* rb0 = xs + (wave * 32 + b16) * EPD + 4 * g;
    const uint* rb1 = rb0 + 16 * EPD;

    // ---- Phase A: conv + relu, both chains, FULL unroll (static B2s idx) ----
    f16x4 B2sA[LSEQ], B2sB[LSEQ];
    #pragma unroll
    for (int l = 0; l < LSEQ; ++l) {
        UB128 B1a, B1b;
        B1a.q = *(const uint4*)(rb0 + 4 * l);
        B1b.q = *(const uint4*)(rb1 + 4 * l);
        f32x4 a1a = __builtin_amdgcn_mfma_f32_16x16x32_f16(A1, B1a.v, zero4, 0, 0, 0);
        f32x4 a1b = __builtin_amdgcn_mfma_f32_16x16x32_f16(A1, B1b.v, zero4, 0, 0, 0);
        UB64 Ba, Bb;
        Ba.p[0] = __builtin_amdgcn_cvt_pkrtz(fmaxf(a1a[0], 0.f), fmaxf(a1a[1], 0.f));
        Ba.p[1] = __builtin_amdgcn_cvt_pkrtz(fmaxf(a1a[2], 0.f), fmaxf(a1a[3], 0.f));
        Bb.p[0] = __builtin_amdgcn_cvt_pkrtz(fmaxf(a1b[0], 0.f), fmaxf(a1b[1], 0.f));
        Bb.p[1] = __builtin_amdgcn_cvt_pkrtz(fmaxf(a1b[2], 0.f), fmaxf(a1b[3], 0.f));
        B2sA[l] = Ba.v;
        B2sB[l] = Bb.v;
    }

    // ---- Phase B: two independent serial recurrences, interleaved ----
    f16x4 H0 = {}, H1 = {};
    #pragma unroll
    for (int l = 0; l < LSEQ; ++l) {
        f32x4 a20 = __builtin_amdgcn_mfma_f32_16x16x16f16(A2, B2sA[l], rbp, 0, 0, 0);
        f32x4 a21 = __builtin_amdgcn_mfma_f32_16x16x16f16(A2, B2sB[l], rbp, 0, 0, 0);
        a20 = __builtin_amdgcn_mfma_f32_16x16x16f16(AU, H0, a20, 0, 0, 0);
        a21 = __builtin_amdgcn_mfma_f32_16x16x16f16(AU, H1, a21, 0, 0, 0);
        float t00 = __builtin_amdgcn_rcpf(1.f + __builtin_amdgcn_exp2f(a20[0]));
        float t01 = __builtin_amdgcn_rcpf(1.f + __builtin_amdgcn_exp2f(a20[1]));
        float t02 = __builtin_amdgcn_rcpf(1.f + __builtin_amdgcn_exp2f(a20[2]));
        float t03 = __builtin_amdgcn_rcpf(1.f + __builtin_amdgcn_exp2f(a20[3]));
        float t10 = __builtin_amdgcn_rcpf(1.f + __builtin_amdgcn_exp2f(a21[0]));
        float t11 = __builtin_amdgcn_rcpf(1.f + __builtin_amdgcn_exp2f(a21[1]));
        float t12 = __builtin_amdgcn_rcpf(1.f + __builtin_amdgcn_exp2f(a21[2]));
        float t13 = __builtin_amdgcn_rcpf(1.f + __builtin_amdgcn_exp2f(a21[3]));
        UB64 Hn0, Hn1;
        Hn0.p[0] = __builtin_amdgcn_cvt_pkrtz(fmaf(-2.f, t00, 1.f), fmaf(-2.f, t01, 1.f));
        Hn0.p[1] = __builtin_amdgcn_cvt_pkrtz(fmaf(-2.f, t02, 1.f), fmaf(-2.f, t03, 1.f));
        Hn1.p[0] = __builtin_amdgcn_cvt_pkrtz(fmaf(-2.f, t10, 1.f), fmaf(-2.f, t11, 1.f));
        Hn1.p[1] = __builtin_amdgcn_cvt_pkrtz(fmaf(-2.f, t12, 1.f), fmaf(-2.f, t13, 1.f));
        H0 = Hn0.v;
        H1 = Hn1.v;
    }

    // ---- head via MFMA (shared A3/c3): z = relu(H @ d1_w + d1_b) @ out_w ----
    f16x4 A3;
    f32x4 c3;
    #pragma unroll
    for (int t = 0; t < 4; ++t) {
        int j = 4 * g + t;
        A3[t] = (f16)(b16 < 8 ? d1_w[j * 8 + b16] : 0.f);
        c3[t] = d1_b[min(j, 7)];                 // rows>=8 garbage (finite)
    }
    f32x4 a30 = __builtin_amdgcn_mfma_f32_16x16x16f16(A3, H0, c3, 0, 0, 0);
    f32x4 a31 = __builtin_amdgcn_mfma_f32_16x16x16f16(A3, H1, c3, 0, 0, 0);
    float p0 = 0.f, p1 = 0.f;
    #pragma unroll
    for (int r = 0; r < 4; ++r) {
        int d = 4 * g + r;                       // valid for g<2
        float wv = (g < 2) ? out_w[min(d, 7)] : 0.f;
        p0 = fmaf(fmaxf(a30[r], 0.f), wv, p0);
        p1 = fmaf(fmaxf(a31[r], 0.f), wv, p1);
    }
    p0 += __shfl_xor(p0, 16); p0 += __shfl_xor(p0, 32);
    p1 += __shfl_xor(p1, 16); p1 += __shfl_xor(p1, 32);
    if (lane < 16) {
        float ob = out_b[0];
        out[BE + wave * 32 + b16]      = p0 + ob;
        out[BE + wave * 32 + 16 + b16] = p1 + ob;
    }
}

extern "C" void kernel_launch(void* const* d_in, const int* in_sizes, int n_in,
                              void* d_out, int out_size, void* d_ws, size_t ws_size,
                              hipStream_t stream) {
    const float* x      = (const float*)d_in[0];
    const float* conv_w = (const float*)d_in[1];
    const float* conv_b = (const float*)d_in[2];
    const float* rnn_w  = (const float*)d_in[3];
    const float* rnn_u  = (const float*)d_in[4];
    const float* rnn_b  = (const float*)d_in[5];
    const float* d1_w   = (const float*)d_in[6];
    const float* d1_b   = (const float*)d_in[7];
    const float* out_w  = (const float*)d_in[8];
    const float* out_b  = (const float*)d_in[9];
    float* out = (float*)d_out;

    const int B = out_size;                 // 262144
    const int grid = B / EPB;               // 2048 blocks
    hybrid_fwd<<<grid, BLK, 0, stream>>>(x, conv_w, conv_b, rnn_w, rnn_u, rnn_b,
                                         d1_w, d1_b, out_w, out_b, out);
}